// Round 12
// baseline (1589.867 us; speedup 1.0000x reference)
//
#include <hip/hip_runtime.h>

// Viterbi decode (CRF): B=128, T=4096, L=64.
// Outputs: score[B] (f32), path[B][T] (written as float labels).
constexpr int kB = 128;
constexpr int kT = 4096;
constexpr int kL = 64;
constexpr int kSeg = 64;     // number of backtrace segments
constexpr int kSegLen = 64;  // rows per segment (last segment has 63)
constexpr float kNeg = -10000.0f;

typedef float f32x2 __attribute__((ext_vector_type(2)));
typedef float f32x4 __attribute__((ext_vector_type(4)));

// ---------------- K1 forward step: LDS broadcast + packed adds --------------
// One wave per batch; lane i owns label i. delta published via ONE
// ds_write_b32, read back as 16 uniform-address ds_read_b128 broadcasts
// (conflict-free; single wave + in-order DS pipe => no barriers/drains).
// The 64 adds tr[i][j]+delta[j] are forced into 32 v_pk_add_f32 via minimal
// inline asm (compiler never emits pk f32 adds on its own; v_pk_max_f32 does
// NOT exist on CDNA so maxes stay scalar, shaped for v_max3_f32 folding).
// Bitwise-exact vs reference: identical IEEE adds; max is order-invariant.
__device__ __forceinline__ float step_pk(const f32x2 (&tr2)[kL / 2], float* dl,
                                         const f32x4* dl4, int i, float d, float f) {
  asm volatile("" ::: "memory");
  dl[i] = d;                       // publish delta(t-1); DS FIFO orders w->r
  asm volatile("" ::: "memory");
  f32x4 v[16];
#pragma unroll
  for (int q = 0; q < 16; ++q) v[q] = dl4[q];  // 16x ds_read_b128 (uniform)
  __builtin_amdgcn_sched_barrier(0);
  float m[16];
#pragma unroll
  for (int q = 0; q < 16; ++q) {
    f32x2 lo, hi;
    asm("v_pk_add_f32 %0, %1, %2" : "=v"(lo) : "v"(tr2[2 * q]), "v"(v[q].lo));
    asm("v_pk_add_f32 %0, %1, %2" : "=v"(hi) : "v"(tr2[2 * q + 1]), "v"(v[q].hi));
    // max3(lo.x,lo.y,hi.x) + max(_,hi.y): 2 instrs
    m[q] = fmaxf(fmaxf(fmaxf(lo.x, lo.y), hi.x), hi.y);
  }
  float g0 = fmaxf(fmaxf(m[0], m[1]), m[2]);      // v_max3_f32 x5
  float g1 = fmaxf(fmaxf(m[3], m[4]), m[5]);
  float g2 = fmaxf(fmaxf(m[6], m[7]), m[8]);
  float g3 = fmaxf(fmaxf(m[9], m[10]), m[11]);
  float g4 = fmaxf(fmaxf(m[12], m[13]), m[14]);
  float h0 = fmaxf(fmaxf(g0, g1), g2);            // v_max3_f32 x2
  float h1 = fmaxf(fmaxf(g3, g4), m[15]);
  return fmaxf(h0, h1) + f;
}

__global__ __launch_bounds__(64, 1) void fwd_delta(const float* __restrict__ feats,
                                                   const float* __restrict__ trans,
                                                   float* __restrict__ delta) {
  const int i = threadIdx.x;
  const int b = blockIdx.x;
  const size_t kBL = (size_t)kB * kL;
  f32x2 tr2[kL / 2];
#pragma unroll
  for (int k = 0; k < kL; k += 4) {
    float4 v = *reinterpret_cast<const float4*>(trans + i * kL + k);
    tr2[k / 2].x = v.x; tr2[k / 2].y = v.y;
    tr2[k / 2 + 1].x = v.z; tr2[k / 2 + 1].y = v.w;
  }
  __shared__ float dl[kL];
  const f32x4* dl4 = reinterpret_cast<const f32x4*>(dl);
  float d = (i == 62) ? 0.0f : kNeg;
  float* drow = delta + (size_t)b * kL + i;  // layout [T][B][L]
  *drow = d;
  drow += kBL;
  const float* fp = feats + (size_t)b * kT * kL + i;
  // 4-deep feat prefetch ring; no clamping in the main loop.
  float f0 = fp[64 * 1], f1 = fp[64 * 2], f2 = fp[64 * 3], f3 = fp[64 * 4];
  const float* pf = fp + 64 * 5;
  for (int it = 0; it < 1022; ++it) {   // steps t=1..4088
    d = step_pk(tr2, dl, dl4, i, d, f0);
    *drow = d; drow += kBL; f0 = pf[0];
    d = step_pk(tr2, dl, dl4, i, d, f1);
    *drow = d; drow += kBL; f1 = pf[64];
    d = step_pk(tr2, dl, dl4, i, d, f2);
    *drow = d; drow += kBL; f2 = pf[128];
    d = step_pk(tr2, dl, dl4, i, d, f3);
    *drow = d; drow += kBL; f3 = pf[192];
    pf += 256;
  }
  // pf now points at row t=4093. Steps remaining: 4089..4095 (7 steps).
  float g0 = pf[0], g1 = pf[64], g2 = pf[128];
  d = step_pk(tr2, dl, dl4, i, d, f0); *drow = d; drow += kBL;
  d = step_pk(tr2, dl, dl4, i, d, f1); *drow = d; drow += kBL;
  d = step_pk(tr2, dl, dl4, i, d, f2); *drow = d; drow += kBL;
  d = step_pk(tr2, dl, dl4, i, d, f3); *drow = d; drow += kBL;
  d = step_pk(tr2, dl, dl4, i, d, g0); *drow = d; drow += kBL;
  d = step_pk(tr2, dl, dl4, i, d, g1); *drow = d; drow += kBL;
  d = step_pk(tr2, dl, dl4, i, d, g2); *drow = d;
}

// ---------------- K2: recompute backpointers from stored delta --------------
// row r = t*128 + b; delta layout [T][B][L] makes row base = delta + r*64.
__global__ __launch_bounds__(256) void psi_from_delta(const float* __restrict__ delta,
                                                      const float* __restrict__ trans,
                                                      unsigned char* __restrict__ psi) {
  const int lane = threadIdx.x & 63;
  const int w = __builtin_amdgcn_readfirstlane(blockIdx.x * 4 + (threadIdx.x >> 6));
  float tr[kL];
#pragma unroll
  for (int k = 0; k < kL; k += 4) {
    float4 v = *reinterpret_cast<const float4*>(trans + lane * kL + k);
    tr[k] = v.x; tr[k + 1] = v.y; tr[k + 2] = v.z; tr[k + 3] = v.w;
  }
  const int r0 = w * 8;  // 8 rows per wave; grid sized exactly
  for (int rr = 0; rr < 8; ++rr) {
    const int r = r0 + rr;
    const float4* row4 = reinterpret_cast<const float4*>(delta + (size_t)r * kL);
    float bA = -INFINITY, bBv = -INFINITY;
    int iA = 0, iB = 32;
#pragma unroll
    for (int q = 0; q < 8; ++q) {
      float4 dv = row4[q];
      float c; bool g;
      c = tr[4 * q + 0] + dv.x; g = c > bA; bA = g ? c : bA; iA = g ? 4 * q + 0 : iA;
      c = tr[4 * q + 1] + dv.y; g = c > bA; bA = g ? c : bA; iA = g ? 4 * q + 1 : iA;
      c = tr[4 * q + 2] + dv.z; g = c > bA; bA = g ? c : bA; iA = g ? 4 * q + 2 : iA;
      c = tr[4 * q + 3] + dv.w; g = c > bA; bA = g ? c : bA; iA = g ? 4 * q + 3 : iA;
    }
#pragma unroll
    for (int q = 8; q < 16; ++q) {
      float4 dv = row4[q];
      float c; bool g;
      c = tr[4 * q + 0] + dv.x; g = c > bBv; bBv = g ? c : bBv; iB = g ? 4 * q + 0 : iB;
      c = tr[4 * q + 1] + dv.y; g = c > bBv; bBv = g ? c : bBv; iB = g ? 4 * q + 1 : iB;
      c = tr[4 * q + 2] + dv.z; g = c > bBv; bBv = g ? c : bBv; iB = g ? 4 * q + 2 : iB;
      c = tr[4 * q + 3] + dv.w; g = c > bBv; bBv = g ? c : bBv; iB = g ? 4 * q + 3 : iB;
    }
    bool gm = bBv > bA;  // tie -> lower half (first occurrence)
    psi[(size_t)r * kL + lane] = (unsigned char)(gm ? iB : iA);
  }
}

// ---------------- K3: segment composition (in-place psi -> M) ----------------
__global__ __launch_bounds__(256) void seg_compose(unsigned char* psiM,
                                                   unsigned char* __restrict__ C) {
  const int lane = threadIdx.x & 63;
  const int w = blockIdx.x * 4 + (threadIdx.x >> 6);
  const int s = w >> 7;
  const int b = w & 127;
  const int tstart = s * kSegLen;
  const int tend = (tstart + kSegLen < kT) ? tstart + kSegLen : kT - 1;  // last seg: 4095
  const size_t stride = (size_t)kB * kL;
  size_t off = ((size_t)(tend - 1) * kB + b) * kL + lane;
  int m = lane;
  int v = psiM[off];
  for (int t = tend - 1; t > tstart; --t) {
    int vn = psiM[off - stride];          // prefetch next row
    m = __shfl(v, m, 64);                 // m = psi_row[m]
    psiM[off] = (unsigned char)m;         // M[t][b][e] = path[t] | hyp e
    v = vn;
    off -= stride;
  }
  m = __shfl(v, m, 64);
  psiM[off] = (unsigned char)m;
  C[((size_t)s * kB + b) * kL + lane] = (unsigned char)m;  // composed map
}

// ---------------- K4: score, last label, boundary-label scan ----------------
__global__ __launch_bounds__(64) void score_scan(const float* __restrict__ dfin,
                                                 const unsigned char* __restrict__ C,
                                                 int* __restrict__ E,
                                                 float* __restrict__ out) {
  const int b = blockIdx.x;
  const int i = threadIdx.x;
  float d = dfin[(size_t)b * kL + i];
  float m = d;
#pragma unroll
  for (int off = 32; off; off >>= 1) m = fmaxf(m, __shfl_xor(m, off, 64));
  unsigned long long msk = __ballot(d == m);
  int ll = __ffsll(msk) - 1;  // first (lowest) argmax lane
  if (i == 0) {
    out[b] = m;
    out[kB + (size_t)b * kT + (kT - 1)] = (float)ll;
    int lbl = ll;
    for (int s = kSeg - 1; s >= 0; --s) {
      E[s * kB + b] = lbl;                              // label at t_end(s)
      lbl = C[((size_t)s * kB + b) * kL + lbl];         // -> label at t_start(s)
    }
  }
}

// ---------------- K5: parallel path gather ----------------
__global__ __launch_bounds__(256) void path_fill(const unsigned char* __restrict__ M,
                                                 const int* __restrict__ E,
                                                 float* __restrict__ out) {
  const int n = blockIdx.x * 256 + threadIdx.x;  // n = b*4096 + t
  const int b = n >> 12;
  const int t = n & (kT - 1);
  if (t == kT - 1) return;  // written by score_scan
  const int e = E[(t >> 6) * kB + b];
  const unsigned char lab = M[((size_t)t * kB + b) * kL + e];
  out[kB + (size_t)b * kT + t] = (float)lab;
}

extern "C" void kernel_launch(void* const* d_in, const int* in_sizes, int n_in,
                              void* d_out, int out_size, void* d_ws, size_t ws_size,
                              hipStream_t stream) {
  const float* feats = (const float*)d_in[0];
  const float* trans = (const float*)d_in[1];
  float* out = (float*)d_out;
  char* ws = (char*)d_ws;

  const size_t deltaB = (size_t)kT * kB * kL * 4;   // 134,217,728
  const size_t psiB   = (size_t)kT * kB * kL;       //  33,554,432
  const size_t CBy    = (size_t)kSeg * kB * kL;     //     524,288

  float* delta = (float*)ws;
  unsigned char* psi = (unsigned char*)(ws + deltaB);
  unsigned char* C = (unsigned char*)(ws + deltaB + psiB);
  int* E = (int*)(ws + deltaB + psiB + CBy);
  hipLaunchKernelGGL(fwd_delta, dim3(kB), dim3(64), 0, stream, feats, trans, delta);
  hipLaunchKernelGGL(psi_from_delta, dim3(16380), dim3(256), 0, stream, delta, trans, psi);
  hipLaunchKernelGGL(seg_compose, dim3(2048), dim3(256), 0, stream, psi, C);
  hipLaunchKernelGGL(score_scan, dim3(kB), dim3(64), 0, stream,
                     delta + (size_t)(kT - 1) * kB * kL, C, E, out);
  hipLaunchKernelGGL(path_fill, dim3(2048), dim3(256), 0, stream, psi, E, out);
}

// Round 14
// 1383.961 us; speedup vs baseline: 1.1488x; 1.1488x over previous
//
#include <hip/hip_runtime.h>

// Viterbi decode (CRF): B=128, T=4096, L=64.
// Outputs: score[B] (f32), path[B][T] (written as float labels).
constexpr int kB = 128;
constexpr int kT = 4096;
constexpr int kL = 64;
constexpr int kSeg = 64;     // number of backtrace segments
constexpr int kSegLen = 64;  // rows per segment (last segment has 63)
constexpr float kNeg = -10000.0f;

typedef float f32x4 __attribute__((ext_vector_type(4)));

// ---------------- shared reduction (identical in both step paths) -----------
// 64 adds tr[j]+delta[j], then max tree shaped for v_max3_f32.
// Max over the same 64 values is order-invariant => the two paths are
// bitwise-identical by construction.
__device__ __forceinline__ float red64(const float (&tr)[kL], const f32x4 (&v)[16],
                                       float f) {
  float m[16];
#pragma unroll
  for (int q = 0; q < 16; ++q) {
    float a0 = tr[4 * q + 0] + v[q].x;
    float a1 = tr[4 * q + 1] + v[q].y;
    float a2 = tr[4 * q + 2] + v[q].z;
    float a3 = tr[4 * q + 3] + v[q].w;
    m[q] = fmaxf(fmaxf(fmaxf(a0, a1), a2), a3);  // v_max3 + v_max
  }
  float g0 = fmaxf(fmaxf(m[0], m[1]), m[2]);     // v_max3_f32 x5
  float g1 = fmaxf(fmaxf(m[3], m[4]), m[5]);
  float g2 = fmaxf(fmaxf(m[6], m[7]), m[8]);
  float g3 = fmaxf(fmaxf(m[9], m[10]), m[11]);
  float g4 = fmaxf(fmaxf(m[12], m[13]), m[14]);
  float h0 = fmaxf(fmaxf(g0, g1), g2);           // v_max3_f32 x2
  float h1 = fmaxf(fmaxf(g3, g4), m[15]);
  return fmaxf(h0, h1) + f;
}

// ---------------- K1 step, fused DS transaction (fast path) -----------------
// ONE asm block: ds_write_b32 + 16x ds_read_b128 (uniform base, offset:imm) +
// s_waitcnt lgkmcnt(0). Unsplittable => all reads in flight together: exactly
// one LDS round-trip per step (compiler load-sinking paid it ~3x: VGPR 72-76,
// ~660cy/step across R5/R7/R12). Addresses come from the REAL __shared__
// array (R13 failed because the raw-offset version let LDS be eliminated).
__device__ __forceinline__ float step_fused(const float (&tr)[kL], int waddr,
                                            int zaddr, float d, float f) {
  f32x4 v[16];
  asm volatile(
      "ds_write_b32 %[wa], %[dv]\n\t"
      "ds_read_b128 %[o0], %[ra] offset:0\n\t"
      "ds_read_b128 %[o1], %[ra] offset:16\n\t"
      "ds_read_b128 %[o2], %[ra] offset:32\n\t"
      "ds_read_b128 %[o3], %[ra] offset:48\n\t"
      "ds_read_b128 %[o4], %[ra] offset:64\n\t"
      "ds_read_b128 %[o5], %[ra] offset:80\n\t"
      "ds_read_b128 %[o6], %[ra] offset:96\n\t"
      "ds_read_b128 %[o7], %[ra] offset:112\n\t"
      "ds_read_b128 %[o8], %[ra] offset:128\n\t"
      "ds_read_b128 %[o9], %[ra] offset:144\n\t"
      "ds_read_b128 %[o10], %[ra] offset:160\n\t"
      "ds_read_b128 %[o11], %[ra] offset:176\n\t"
      "ds_read_b128 %[o12], %[ra] offset:192\n\t"
      "ds_read_b128 %[o13], %[ra] offset:208\n\t"
      "ds_read_b128 %[o14], %[ra] offset:224\n\t"
      "ds_read_b128 %[o15], %[ra] offset:240\n\t"
      "s_waitcnt lgkmcnt(0)"
      : [o0] "=v"(v[0]), [o1] "=v"(v[1]), [o2] "=v"(v[2]), [o3] "=v"(v[3]),
        [o4] "=v"(v[4]), [o5] "=v"(v[5]), [o6] "=v"(v[6]), [o7] "=v"(v[7]),
        [o8] "=v"(v[8]), [o9] "=v"(v[9]), [o10] "=v"(v[10]), [o11] "=v"(v[11]),
        [o12] "=v"(v[12]), [o13] "=v"(v[13]), [o14] "=v"(v[14]), [o15] "=v"(v[15])
      : [wa] "v"(waddr), [dv] "v"(d), [ra] "v"(zaddr)
      : "memory");
  return red64(tr, v, f);
}

// ---------------- K1 step, plain-C LDS broadcast (exact fallback) -----------
__device__ __forceinline__ float step_ldsC(const float (&tr)[kL], float* dl,
                                           const f32x4* dl4, int i, float d, float f) {
  asm volatile("" ::: "memory");
  dl[i] = d;
  asm volatile("" ::: "memory");
  f32x4 v[16];
#pragma unroll
  for (int q = 0; q < 16; ++q) v[q] = dl4[q];
  __builtin_amdgcn_sched_barrier(0);
  return red64(tr, v, f);
}

__global__ __launch_bounds__(64, 1) void fwd_delta(const float* __restrict__ feats,
                                                   const float* __restrict__ trans,
                                                   float* __restrict__ delta) {
  const int i = threadIdx.x;
  const int b = blockIdx.x;
  const size_t kBL = (size_t)kB * kL;
  float tr[kL];
#pragma unroll
  for (int k = 0; k < kL; k += 4) {
    float4 v = *reinterpret_cast<const float4*>(trans + i * kL + k);
    tr[k] = v.x; tr[k + 1] = v.y; tr[k + 2] = v.z; tr[k + 3] = v.w;
  }
  __shared__ float dl[kL];
  const f32x4* dl4 = reinterpret_cast<const f32x4*>(dl);
  // LDS byte offsets: low 32 bits of the flat pointer (4GB-aligned aperture).
  const unsigned ldsbase = (unsigned)(uintptr_t)(&dl[0]);
  const int waddr = (int)(ldsbase + 4u * (unsigned)i);
  const int zaddr = (int)ldsbase;

  float d = (i == 62) ? 0.0f : kNeg;
  float* drow = delta + (size_t)b * kL + i;  // layout [T][B][L]
  *drow = d;
  drow += kBL;
  const float* fp = feats + (size_t)b * kT * kL + i;
  float fA = fp[64 * 1], fB = fp[64 * 2], fC = fp[64 * 3], fD = fp[64 * 4];

  // ---- verify step t=1: fused-asm path vs plain-C path, bitwise ----
  float dF = step_fused(tr, waddr, zaddr, d, fA);
  float dE = step_ldsC(tr, dl, dl4, i, d, fA);
  const bool ok = __all(__float_as_int(dF) == __float_as_int(dE)) != 0;
  d = dE;
  *drow = d;
  drow += kBL;
  fA = fp[64 * 5];
  const float* pf = fp + 64 * 6;

  if (ok) {
    for (int it = 0; it < 1022; ++it) {  // steps t=2..4089
      d = step_fused(tr, waddr, zaddr, d, fB); *drow = d; drow += kBL; fB = pf[0];
      d = step_fused(tr, waddr, zaddr, d, fC); *drow = d; drow += kBL; fC = pf[64];
      d = step_fused(tr, waddr, zaddr, d, fD); *drow = d; drow += kBL; fD = pf[128];
      d = step_fused(tr, waddr, zaddr, d, fA); *drow = d; drow += kBL; fA = pf[192];
      pf += 256;
    }
    float g0 = pf[0], g1 = pf[64];  // t=4094, 4095
    d = step_fused(tr, waddr, zaddr, d, fB); *drow = d; drow += kBL;
    d = step_fused(tr, waddr, zaddr, d, fC); *drow = d; drow += kBL;
    d = step_fused(tr, waddr, zaddr, d, fD); *drow = d; drow += kBL;
    d = step_fused(tr, waddr, zaddr, d, fA); *drow = d; drow += kBL;
    d = step_fused(tr, waddr, zaddr, d, g0); *drow = d; drow += kBL;
    d = step_fused(tr, waddr, zaddr, d, g1); *drow = d;
  } else {
    for (int it = 0; it < 1022; ++it) {
      d = step_ldsC(tr, dl, dl4, i, d, fB); *drow = d; drow += kBL; fB = pf[0];
      d = step_ldsC(tr, dl, dl4, i, d, fC); *drow = d; drow += kBL; fC = pf[64];
      d = step_ldsC(tr, dl, dl4, i, d, fD); *drow = d; drow += kBL; fD = pf[128];
      d = step_ldsC(tr, dl, dl4, i, d, fA); *drow = d; drow += kBL; fA = pf[192];
      pf += 256;
    }
    float g0 = pf[0], g1 = pf[64];
    d = step_ldsC(tr, dl, dl4, i, d, fB); *drow = d; drow += kBL;
    d = step_ldsC(tr, dl, dl4, i, d, fC); *drow = d; drow += kBL;
    d = step_ldsC(tr, dl, dl4, i, d, fD); *drow = d; drow += kBL;
    d = step_ldsC(tr, dl, dl4, i, d, fA); *drow = d; drow += kBL;
    d = step_ldsC(tr, dl, dl4, i, d, g0); *drow = d; drow += kBL;
    d = step_ldsC(tr, dl, dl4, i, d, g1); *drow = d;
  }
}

// ---------------- K2: recompute backpointers from stored delta --------------
// row r = t*128 + b; delta layout [T][B][L] makes row base = delta + r*64.
__global__ __launch_bounds__(256) void psi_from_delta(const float* __restrict__ delta,
                                                      const float* __restrict__ trans,
                                                      unsigned char* __restrict__ psi) {
  const int lane = threadIdx.x & 63;
  const int w = __builtin_amdgcn_readfirstlane(blockIdx.x * 4 + (threadIdx.x >> 6));
  float tr[kL];
#pragma unroll
  for (int k = 0; k < kL; k += 4) {
    float4 v = *reinterpret_cast<const float4*>(trans + lane * kL + k);
    tr[k] = v.x; tr[k + 1] = v.y; tr[k + 2] = v.z; tr[k + 3] = v.w;
  }
  const int r0 = w * 8;  // 8 rows per wave; grid sized exactly
  for (int rr = 0; rr < 8; ++rr) {
    const int r = r0 + rr;
    const float4* row4 = reinterpret_cast<const float4*>(delta + (size_t)r * kL);
    float bA = -INFINITY, bBv = -INFINITY;
    int iA = 0, iB = 32;
#pragma unroll
    for (int q = 0; q < 8; ++q) {
      float4 dv = row4[q];
      float c; bool g;
      c = tr[4 * q + 0] + dv.x; g = c > bA; bA = g ? c : bA; iA = g ? 4 * q + 0 : iA;
      c = tr[4 * q + 1] + dv.y; g = c > bA; bA = g ? c : bA; iA = g ? 4 * q + 1 : iA;
      c = tr[4 * q + 2] + dv.z; g = c > bA; bA = g ? c : bA; iA = g ? 4 * q + 2 : iA;
      c = tr[4 * q + 3] + dv.w; g = c > bA; bA = g ? c : bA; iA = g ? 4 * q + 3 : iA;
    }
#pragma unroll
    for (int q = 8; q < 16; ++q) {
      float4 dv = row4[q];
      float c; bool g;
      c = tr[4 * q + 0] + dv.x; g = c > bBv; bBv = g ? c : bBv; iB = g ? 4 * q + 0 : iB;
      c = tr[4 * q + 1] + dv.y; g = c > bBv; bBv = g ? c : bBv; iB = g ? 4 * q + 1 : iB;
      c = tr[4 * q + 2] + dv.z; g = c > bBv; bBv = g ? c : bBv; iB = g ? 4 * q + 2 : iB;
      c = tr[4 * q + 3] + dv.w; g = c > bBv; bBv = g ? c : bBv; iB = g ? 4 * q + 3 : iB;
    }
    bool gm = bBv > bA;  // tie -> lower half (first occurrence)
    psi[(size_t)r * kL + lane] = (unsigned char)(gm ? iB : iA);
  }
}

// ---------------- K3: segment composition (in-place psi -> M) ----------------
__global__ __launch_bounds__(256) void seg_compose(unsigned char* psiM,
                                                   unsigned char* __restrict__ C) {
  const int lane = threadIdx.x & 63;
  const int w = blockIdx.x * 4 + (threadIdx.x >> 6);
  const int s = w >> 7;
  const int b = w & 127;
  const int tstart = s * kSegLen;
  const int tend = (tstart + kSegLen < kT) ? tstart + kSegLen : kT - 1;  // last seg: 4095
  const size_t stride = (size_t)kB * kL;
  size_t off = ((size_t)(tend - 1) * kB + b) * kL + lane;
  int m = lane;
  int v = psiM[off];
  for (int t = tend - 1; t > tstart; --t) {
    int vn = psiM[off - stride];          // prefetch next row
    m = __shfl(v, m, 64);                 // m = psi_row[m]
    psiM[off] = (unsigned char)m;         // M[t][b][e] = path[t] | hyp e
    v = vn;
    off -= stride;
  }
  m = __shfl(v, m, 64);
  psiM[off] = (unsigned char)m;
  C[((size_t)s * kB + b) * kL + lane] = (unsigned char)m;  // composed map
}

// ---------------- K4: score, last label, boundary-label scan ----------------
__global__ __launch_bounds__(64) void score_scan(const float* __restrict__ dfin,
                                                 const unsigned char* __restrict__ C,
                                                 int* __restrict__ E,
                                                 float* __restrict__ out) {
  const int b = blockIdx.x;
  const int i = threadIdx.x;
  float d = dfin[(size_t)b * kL + i];
  float m = d;
#pragma unroll
  for (int off = 32; off; off >>= 1) m = fmaxf(m, __shfl_xor(m, off, 64));
  unsigned long long msk = __ballot(d == m);
  int ll = __ffsll(msk) - 1;  // first (lowest) argmax lane
  if (i == 0) {
    out[b] = m;
    out[kB + (size_t)b * kT + (kT - 1)] = (float)ll;
    int lbl = ll;
    for (int s = kSeg - 1; s >= 0; --s) {
      E[s * kB + b] = lbl;                              // label at t_end(s)
      lbl = C[((size_t)s * kB + b) * kL + lbl];         // -> label at t_start(s)
    }
  }
}

// ---------------- K5: parallel path gather ----------------
__global__ __launch_bounds__(256) void path_fill(const unsigned char* __restrict__ M,
                                                 const int* __restrict__ E,
                                                 float* __restrict__ out) {
  const int n = blockIdx.x * 256 + threadIdx.x;  // n = b*4096 + t
  const int b = n >> 12;
  const int t = n & (kT - 1);
  if (t == kT - 1) return;  // written by score_scan
  const int e = E[(t >> 6) * kB + b];
  const unsigned char lab = M[((size_t)t * kB + b) * kL + e];
  out[kB + (size_t)b * kT + t] = (float)lab;
}

extern "C" void kernel_launch(void* const* d_in, const int* in_sizes, int n_in,
                              void* d_out, int out_size, void* d_ws, size_t ws_size,
                              hipStream_t stream) {
  const float* feats = (const float*)d_in[0];
  const float* trans = (const float*)d_in[1];
  float* out = (float*)d_out;
  char* ws = (char*)d_ws;

  const size_t deltaB = (size_t)kT * kB * kL * 4;   // 134,217,728
  const size_t psiB   = (size_t)kT * kB * kL;       //  33,554,432
  const size_t CBy    = (size_t)kSeg * kB * kL;     //     524,288

  float* delta = (float*)ws;
  unsigned char* psi = (unsigned char*)(ws + deltaB);
  unsigned char* C = (unsigned char*)(ws + deltaB + psiB);
  int* E = (int*)(ws + deltaB + psiB + CBy);
  hipLaunchKernelGGL(fwd_delta, dim3(kB), dim3(64), 0, stream, feats, trans, delta);
  hipLaunchKernelGGL(psi_from_delta, dim3(16380), dim3(256), 0, stream, delta, trans, psi);
  hipLaunchKernelGGL(seg_compose, dim3(2048), dim3(256), 0, stream, psi, C);
  hipLaunchKernelGGL(score_scan, dim3(kB), dim3(64), 0, stream,
                     delta + (size_t)(kT - 1) * kB * kL, C, E, out);
  hipLaunchKernelGGL(path_fill, dim3(2048), dim3(256), 0, stream, psi, E, out);
}